// Round 3
// baseline (126.778 us; speedup 1.0000x reference)
//
#include <hip/hip_runtime.h>
#include <hip/hip_bf16.h>

#define N_PTS 65536
#define LOG2E 1.4426950408889634f

typedef __attribute__((ext_vector_type(8))) short short8;
typedef __attribute__((ext_vector_type(4))) float float4v;

#if __has_builtin(__builtin_amdgcn_exp2f)
#define EXP2F(x) __builtin_amdgcn_exp2f(x)
#else
#define EXP2F(x) exp2f(x)
#endif

__device__ __forceinline__ short f2b(float f) {
    __hip_bfloat16 h = __float2bfloat16(f);
    return *(short*)&h;
}
__device__ __forceinline__ float b2f(short s) {
    __hip_bfloat16 h = *(__hip_bfloat16*)&s;
    return __bfloat162float(h);
}

// K-permutation: within each 32-row group, storage row p holds source row
// perm(p). Chunk A (p<16) -> m {0-3,8-11,16-19,24-27}; chunk B -> +4.
// Producer D-reg r at lane q (chunk A row 4q+r) => m = 8q+r; chunk B => 8q+4+r.
// So [dA[0..3], dB[0..3]] at lane q == consumer B-fragment k = 8q..8q+7. No LDS.
__device__ __forceinline__ int permrow(int p) {
    return ((p & 12) << 1) + (p & 3) + ((p >> 4) << 2);
}

// ---------------- prep (unchanged) ----------------
// ws layout (bytes):
//   zb   [1024][16] bf16  @ 0        row-PERMUTED bf16(log2e * z)
//   FbB  [512][16] bf16   @ 32768    row-PERMUTED F^T (rows = o*64+l)
//   BWd  [64][512] bf16   @ 49152    block-diag sqrt(2/64)*pw (natural cols)
//   Wtb  [64][1024] bf16  @ 114688   bf16(W) (natural cols)
//   nz2P [1024] f32       @ 245760   PERMUTED  -0.5*log2e*||bf16(z_m)||^2
//   phP  [512] f32        @ 249856   PERMUTED  phases
__global__ __launch_bounds__(256) void prep_kernel(
    const float* __restrict__ z, const float* __restrict__ W,
    const float* __restrict__ F, const float* __restrict__ pw,
    const float* __restrict__ ph,
    short* __restrict__ zb, short* __restrict__ FbB,
    short* __restrict__ BWd, short* __restrict__ Wtb,
    float* __restrict__ nz2P, float* __restrict__ phP)
{
    int t = blockIdx.x * 256 + threadIdx.x;
    if (t < 16384) {
        int row = t >> 4, i = t & 15;
        int src = (row & ~31) + permrow(row & 31);
        zb[t] = f2b(LOG2E * z[src * 16 + i]);
    } else if (t < 17408) {
        int m = t - 16384;
        int src = (m & ~31) + permrow(m & 31);
        const float4v* zp = (const float4v*)(z + (size_t)src * 16);
        float s = 0.f;
        #pragma unroll
        for (int k = 0; k < 4; k++) {
            float4v v = zp[k];
            float a0 = b2f(f2b(v.x)), a1 = b2f(f2b(v.y));
            float a2 = b2f(f2b(v.z)), a3 = b2f(f2b(v.w));
            s += a0 * a0 + a1 * a1 + a2 * a2 + a3 * a3;
        }
        nz2P[m] = -(0.5f * LOG2E * s);
    } else if (t < 25600) {
        int p = t - 17408;
        int row = p >> 4, i = p & 15;
        int srow = (row & ~31) + permrow(row & 31);
        int o = srow >> 6, l = srow & 63;
        FbB[p] = f2b(F[o * 1024 + i * 64 + l]);
    } else if (t < 58368) {
        int p = t - 25600;
        int so = p >> 9, ol = p & 511, o = ol >> 6;
        float v = ((so & 7) == o) ? 0.17677669529663687f * pw[so * 64 + (ol & 63)] : 0.f;
        BWd[p] = f2b(v);
    } else if (t < 123904) {
        int p = t - 58368;
        Wtb[p] = f2b(W[p]);
    } else {
        int j = t - 123904;                    // 512 phases
        int sj = (j & ~31) + permrow(j & 31);
        phP[j] = ph[sj];
    }
}

// ---------------- fused: register-direct, n-block 32, reg double-buffer ----
// grid 2048, 4 waves/block, wave owns K-quarter (256 m / 128 l) for 64 so x
// 32 n. acc[4][2] = 32 AGPR frees registers for a 1-iteration-deep register
// prefetch of (bz, c0, aw[0..3]) so L2 latency hides under MFMA+trans.
// Zero main-loop LDS/barriers; 4-partial LDS reduction at the end.
__global__ __launch_bounds__(256, 4) void fused_kernel(
    const float* __restrict__ x,
    const short* __restrict__ zb, const short* __restrict__ FbB,
    const short* __restrict__ BWd, const short* __restrict__ Wtb,
    const float* __restrict__ nz2P, const float* __restrict__ phP,
    float* __restrict__ out)
{
    __shared__ float x2c[32];
    __shared__ __align__(16) float rbufA[64 * 34];
    __shared__ __align__(16) float rbufB[64 * 34];

    const int tid = threadIdx.x;
    const int lane = tid & 63, w = tid >> 6;
    const int q = lane >> 4, c = lane & 15;
    const int n0 = blockIdx.x * 32;

    if (tid < 32) {
        float s = 0.f;
        const float4v* xr = (const float4v*)(x + (size_t)(n0 + tid) * 16);
        #pragma unroll
        for (int k = 0; k < 4; k++) {
            float4v v = xr[k];
            float a0 = b2f(f2b(v.x)), a1 = b2f(f2b(v.y));
            float a2 = b2f(f2b(v.z)), a3 = b2f(f2b(v.w));
            s += a0 * a0 + a1 * a1 + a2 * a2 + a3 * a3;
        }
        x2c[tid] = 0.5f * LOG2E * s;
    }

    // x B-fragments for the 2 n-groups (K=16 real, quads 2,3 zero)
    short8 ax[2];
    #pragma unroll
    for (int nt = 0; nt < 2; nt++) {
        ax[nt] = (short8)0;
        if (q < 2) {
            const float4v* xp = (const float4v*)(x + (size_t)(n0 + nt * 16 + c) * 16 + q * 8);
            float4v v0 = xp[0], v1 = xp[1];
            ax[nt][0] = f2b(v0.x); ax[nt][1] = f2b(v0.y);
            ax[nt][2] = f2b(v0.z); ax[nt][3] = f2b(v0.w);
            ax[nt][4] = f2b(v1.x); ax[nt][5] = f2b(v1.y);
            ax[nt][6] = f2b(v1.z); ax[nt][7] = f2b(v1.w);
        }
    }

    float4v acc[4][2];
    #pragma unroll
    for (int a = 0; a < 4; a++)
        #pragma unroll
        for (int nt = 0; nt < 2; nt++) acc[a][nt] = (float4v)(0.f);

    const int mbase = w * 256;
    const int lbase = w * 128;

    // prefetch data iter 0 (before the x2c barrier — no dependency)
    short8 bzA = (short8)0, bzB = (short8)0;
    float4v c0A, c0B;
    short8 aw0, aw1, aw2, aw3;
    {
        const int m0 = mbase;
        if (q < 2) {
            bzA = *(const short8*)(zb + (size_t)(m0 + c) * 16 + q * 8);
            bzB = *(const short8*)(zb + (size_t)(m0 + 16 + c) * 16 + q * 8);
        }
        c0A = *(const float4v*)(nz2P + m0 + 4 * q);
        c0B = *(const float4v*)(nz2P + m0 + 16 + 4 * q);
        aw0 = *(const short8*)(Wtb + (size_t)(0 * 16 + c) * 1024 + m0 + q * 8);
        aw1 = *(const short8*)(Wtb + (size_t)(1 * 16 + c) * 1024 + m0 + q * 8);
        aw2 = *(const short8*)(Wtb + (size_t)(2 * 16 + c) * 1024 + m0 + q * 8);
        aw3 = *(const short8*)(Wtb + (size_t)(3 * 16 + c) * 1024 + m0 + q * 8);
    }

    __syncthreads();   // x2c ready

    // ============ data: exp2(x.z*log2e - z2) @ W^T, wave-private 256 m ============
    #pragma unroll
    for (int mb = 0; mb < 8; mb++) {
        // current iteration's operands
        short8 cbzA = bzA, cbzB = bzB;
        float4v cc0A = c0A, cc0B = c0B;
        short8 ca0 = aw0, ca1 = aw1, ca2 = aw2, ca3 = aw3;
        // issue next iteration's loads (hidden under compute below)
        if (mb < 7) {
            const int m1 = mbase + (mb + 1) * 32;
            if (q < 2) {
                bzA = *(const short8*)(zb + (size_t)(m1 + c) * 16 + q * 8);
                bzB = *(const short8*)(zb + (size_t)(m1 + 16 + c) * 16 + q * 8);
            }
            c0A = *(const float4v*)(nz2P + m1 + 4 * q);
            c0B = *(const float4v*)(nz2P + m1 + 16 + 4 * q);
            aw0 = *(const short8*)(Wtb + (size_t)(0 * 16 + c) * 1024 + m1 + q * 8);
            aw1 = *(const short8*)(Wtb + (size_t)(1 * 16 + c) * 1024 + m1 + q * 8);
            aw2 = *(const short8*)(Wtb + (size_t)(2 * 16 + c) * 1024 + m1 + q * 8);
            aw3 = *(const short8*)(Wtb + (size_t)(3 * 16 + c) * 1024 + m1 + q * 8);
        }
        short8 pb[2];
        #pragma unroll
        for (int nt = 0; nt < 2; nt++) {
            float4v dA = __builtin_amdgcn_mfma_f32_16x16x32_bf16(cbzA, ax[nt], cc0A, 0, 0, 0);
            float4v dB = __builtin_amdgcn_mfma_f32_16x16x32_bf16(cbzB, ax[nt], cc0B, 0, 0, 0);
            short8 t;
            t[0] = f2b(EXP2F(dA[0])); t[1] = f2b(EXP2F(dA[1]));
            t[2] = f2b(EXP2F(dA[2])); t[3] = f2b(EXP2F(dA[3]));
            t[4] = f2b(EXP2F(dB[0])); t[5] = f2b(EXP2F(dB[1]));
            t[6] = f2b(EXP2F(dB[2])); t[7] = f2b(EXP2F(dB[3]));
            pb[nt] = t;
        }
        #pragma unroll
        for (int nt = 0; nt < 2; nt++) {
            acc[0][nt] = __builtin_amdgcn_mfma_f32_16x16x32_bf16(ca0, pb[nt], acc[0][nt], 0, 0, 0);
            acc[1][nt] = __builtin_amdgcn_mfma_f32_16x16x32_bf16(ca1, pb[nt], acc[1][nt], 0, 0, 0);
            acc[2][nt] = __builtin_amdgcn_mfma_f32_16x16x32_bf16(ca2, pb[nt], acc[2][nt], 0, 0, 0);
            acc[3][nt] = __builtin_amdgcn_mfma_f32_16x16x32_bf16(ca3, pb[nt], acc[3][nt], 0, 0, 0);
        }
    }

    // prefetch prior iter 0 before the scale pass
    {
        const int l0 = lbase;
        if (q < 2) {
            bzA = *(const short8*)(FbB + (size_t)(l0 + c) * 16 + q * 8);
            bzB = *(const short8*)(FbB + (size_t)(l0 + 16 + c) * 16 + q * 8);
        }
        c0A = *(const float4v*)(phP + l0 + 4 * q);
        c0B = *(const float4v*)(phP + l0 + 16 + 4 * q);
        aw0 = *(const short8*)(BWd + (size_t)(0 * 16 + c) * 512 + l0 + q * 8);
        aw1 = *(const short8*)(BWd + (size_t)(1 * 16 + c) * 512 + l0 + q * 8);
        aw2 = *(const short8*)(BWd + (size_t)(2 * 16 + c) * 512 + l0 + q * 8);
        aw3 = *(const short8*)(BWd + (size_t)(3 * 16 + c) * 512 + l0 + q * 8);
    }

    // scale data part by exp2(-x2[n])
    #pragma unroll
    for (int nt = 0; nt < 2; nt++) {
        float sxv = EXP2F(-x2c[nt * 16 + c]);
        #pragma unroll
        for (int a = 0; a < 4; a++) acc[a][nt] *= sxv;
    }

    // ============ prior: cos(x.F + ph) @ blockdiag(pws), wave-private 128 l ============
    #pragma unroll
    for (int lb = 0; lb < 4; lb++) {
        short8 cbzA = bzA, cbzB = bzB;
        float4v cc0A = c0A, cc0B = c0B;
        short8 ca0 = aw0, ca1 = aw1, ca2 = aw2, ca3 = aw3;
        if (lb < 3) {
            const int l1 = lbase + (lb + 1) * 32;
            if (q < 2) {
                bzA = *(const short8*)(FbB + (size_t)(l1 + c) * 16 + q * 8);
                bzB = *(const short8*)(FbB + (size_t)(l1 + 16 + c) * 16 + q * 8);
            }
            c0A = *(const float4v*)(phP + l1 + 4 * q);
            c0B = *(const float4v*)(phP + l1 + 16 + 4 * q);
            aw0 = *(const short8*)(BWd + (size_t)(0 * 16 + c) * 512 + l1 + q * 8);
            aw1 = *(const short8*)(BWd + (size_t)(1 * 16 + c) * 512 + l1 + q * 8);
            aw2 = *(const short8*)(BWd + (size_t)(2 * 16 + c) * 512 + l1 + q * 8);
            aw3 = *(const short8*)(BWd + (size_t)(3 * 16 + c) * 512 + l1 + q * 8);
        }
        short8 pb[2];
        #pragma unroll
        for (int nt = 0; nt < 2; nt++) {
            float4v dA = __builtin_amdgcn_mfma_f32_16x16x32_bf16(cbzA, ax[nt], cc0A, 0, 0, 0);
            float4v dB = __builtin_amdgcn_mfma_f32_16x16x32_bf16(cbzB, ax[nt], cc0B, 0, 0, 0);
            short8 t;
            t[0] = f2b(__cosf(dA[0])); t[1] = f2b(__cosf(dA[1]));
            t[2] = f2b(__cosf(dA[2])); t[3] = f2b(__cosf(dA[3]));
            t[4] = f2b(__cosf(dB[0])); t[5] = f2b(__cosf(dB[1]));
            t[6] = f2b(__cosf(dB[2])); t[7] = f2b(__cosf(dB[3]));
            pb[nt] = t;
        }
        #pragma unroll
        for (int nt = 0; nt < 2; nt++) {
            acc[0][nt] = __builtin_amdgcn_mfma_f32_16x16x32_bf16(ca0, pb[nt], acc[0][nt], 0, 0, 0);
            acc[1][nt] = __builtin_amdgcn_mfma_f32_16x16x32_bf16(ca1, pb[nt], acc[1][nt], 0, 0, 0);
            acc[2][nt] = __builtin_amdgcn_mfma_f32_16x16x32_bf16(ca2, pb[nt], acc[2][nt], 0, 0, 0);
            acc[3][nt] = __builtin_amdgcn_mfma_f32_16x16x32_bf16(ca3, pb[nt], acc[3][nt], 0, 0, 0);
        }
    }

    // ============ epilogue: reduce 4 wave-partials, store ============
    __syncthreads();
    if (w & 1) {                       // w1 -> A, w3 -> B
        float* rb = (w == 1) ? rbufA : rbufB;
        #pragma unroll
        for (int a = 0; a < 4; a++)
            #pragma unroll
            for (int nt = 0; nt < 2; nt++)
                #pragma unroll
                for (int r = 0; r < 4; r++)
                    rb[(a * 16 + 4 * q + r) * 34 + nt * 16 + c] = acc[a][nt][r];
    }
    __syncthreads();
    if (!(w & 1)) {                    // w0 += into A, w2 += into B
        float* rb = (w == 0) ? rbufA : rbufB;
        #pragma unroll
        for (int a = 0; a < 4; a++)
            #pragma unroll
            for (int nt = 0; nt < 2; nt++)
                #pragma unroll
                for (int r = 0; r < 4; r++) {
                    int idx = (a * 16 + 4 * q + r) * 34 + nt * 16 + c;
                    rb[idx] += acc[a][nt][r];
                }
    }
    __syncthreads();
    #pragma unroll
    for (int k = 0; k < 8; k++) {      // out = A + B, row-coalesced (2048 vals)
        int idx = k * 256 + tid;
        int row = idx >> 5, nn = idx & 31;
        out[(size_t)row * N_PTS + n0 + nn] = rbufA[row * 34 + nn] + rbufB[row * 34 + nn];
    }
}

extern "C" void kernel_launch(void* const* d_in, const int* in_sizes, int n_in,
                              void* d_out, int out_size, void* d_ws, size_t ws_size,
                              hipStream_t stream) {
    const float* x  = (const float*)d_in[0];   // [65536][16]
    const float* z  = (const float*)d_in[1];   // [1024][16]
    const float* W  = (const float*)d_in[2];   // [8][8][1024] = [64][1024]
    const float* F  = (const float*)d_in[3];   // [8][16][64]
    const float* ph = (const float*)d_in[4];   // [8][64]
    const float* pw = (const float*)d_in[5];   // [8][8][64] = [64][64]
    float* out = (float*)d_out;                // [64][65536]

    char* ws = (char*)d_ws;
    short* zb   = (short*)(ws);            // 32768 B
    short* FbB  = (short*)(ws + 32768);    // 16384 B
    short* BWd  = (short*)(ws + 49152);    // 65536 B
    short* Wtb  = (short*)(ws + 114688);   // 131072 B
    float* nz2P = (float*)(ws + 245760);   // 4096 B
    float* phP  = (float*)(ws + 249856);   // 2048 B

    prep_kernel<<<486, 256, 0, stream>>>(z, W, F, pw, ph, zb, FbB, BWd, Wtb, nz2P, phP);
    fused_kernel<<<2048, 256, 0, stream>>>(x, zb, FbB, BWd, Wtb, nz2P, phP, out);
}

// Round 5
// 115.287 us; speedup vs baseline: 1.0997x; 1.0997x over previous
//
#include <hip/hip_runtime.h>
#include <hip/hip_bf16.h>

#define N_PTS 65536
#define LOG2E 1.4426950408889634f
#define INV2PI 0.15915494309189535f

typedef __attribute__((ext_vector_type(8))) short short8;
typedef __attribute__((ext_vector_type(4))) float float4v;
typedef __attribute__((ext_vector_type(4))) unsigned int uint4v;

#if __has_builtin(__builtin_amdgcn_exp2f)
#define EXP2F(x) __builtin_amdgcn_exp2f(x)
#else
#define EXP2F(x) exp2f(x)
#endif

// cos on REVOLUTIONS (inputs pre-scaled by 1/2pi in prep): v_fract + v_cos.
#if __has_builtin(__builtin_amdgcn_cosf) && __has_builtin(__builtin_amdgcn_fractf)
#define COSR(x) __builtin_amdgcn_cosf(__builtin_amdgcn_fractf(x))
#else
#define COSR(x) __cosf((x) * 6.283185307179586f)
#endif

__device__ __forceinline__ short f2b(float f) {
    __hip_bfloat16 h = __float2bfloat16(f);
    return *(short*)&h;
}
__device__ __forceinline__ float b2f(short s) {
    __hip_bfloat16 h = *(__hip_bfloat16*)&s;
    return __bfloat162float(h);
}

// Packed f32x2 -> bf16x2 via the documented HIP API (round-nearest).
// Compiler may lower to the packed HW cvt; semantics guaranteed either way.
__device__ __forceinline__ unsigned int pk2(float a, float b) {
    union { __hip_bfloat162 h; unsigned int u; } cv;
    cv.h = __float22bfloat162_rn(make_float2(a, b));
    return cv.u;
}

// K-permutation: within each 32-row group, storage row p holds source row
// perm(p). Chunk A (p<16) -> m {0-3,8-11,16-19,24-27}; chunk B -> +4.
// Producer D-reg r at lane q (chunk A row 4q+r) => m = 8q+r; chunk B => 8q+4+r.
// So [dA[0..3], dB[0..3]] at lane q == consumer B-fragment k = 8q..8q+7. No LDS.
__device__ __forceinline__ int permrow(int p) {
    return ((p & 12) << 1) + (p & 3) + ((p >> 4) << 2);
}

// ---------------- prep ----------------
// ws layout (bytes):
//   zb   [1024][16] bf16  @ 0        row-PERMUTED bf16(log2e * z)
//   FbB  [512][16] bf16   @ 32768    row-PERMUTED bf16(F^T / 2pi)  (rows = o*64+l)
//   BWd  [64][512] bf16   @ 49152    block-diag sqrt(2/64)*pw (natural cols)
//   Wtb  [64][1024] bf16  @ 114688   bf16(W) (natural cols)
//   nz2P [1024] f32       @ 245760   PERMUTED  -0.5*log2e*||bf16(z_m)||^2
//   phP  [512] f32        @ 249856   PERMUTED  phases / 2pi
__global__ __launch_bounds__(256) void prep_kernel(
    const float* __restrict__ z, const float* __restrict__ W,
    const float* __restrict__ F, const float* __restrict__ pw,
    const float* __restrict__ ph,
    short* __restrict__ zb, short* __restrict__ FbB,
    short* __restrict__ BWd, short* __restrict__ Wtb,
    float* __restrict__ nz2P, float* __restrict__ phP)
{
    int t = blockIdx.x * 256 + threadIdx.x;
    if (t < 16384) {
        int row = t >> 4, i = t & 15;
        int src = (row & ~31) + permrow(row & 31);
        zb[t] = f2b(LOG2E * z[src * 16 + i]);
    } else if (t < 17408) {
        int m = t - 16384;
        int src = (m & ~31) + permrow(m & 31);
        const float4v* zp = (const float4v*)(z + (size_t)src * 16);
        float s = 0.f;
        #pragma unroll
        for (int k = 0; k < 4; k++) {
            float4v v = zp[k];
            float a0 = b2f(f2b(v.x)), a1 = b2f(f2b(v.y));
            float a2 = b2f(f2b(v.z)), a3 = b2f(f2b(v.w));
            s += a0 * a0 + a1 * a1 + a2 * a2 + a3 * a3;
        }
        nz2P[m] = -(0.5f * LOG2E * s);
    } else if (t < 25600) {
        int p = t - 17408;
        int row = p >> 4, i = p & 15;
        int srow = (row & ~31) + permrow(row & 31);
        int o = srow >> 6, l = srow & 63;
        FbB[p] = f2b(INV2PI * F[o * 1024 + i * 64 + l]);
    } else if (t < 58368) {
        int p = t - 25600;
        int so = p >> 9, ol = p & 511, o = ol >> 6;
        float v = ((so & 7) == o) ? 0.17677669529663687f * pw[so * 64 + (ol & 63)] : 0.f;
        BWd[p] = f2b(v);
    } else if (t < 123904) {
        int p = t - 58368;
        Wtb[p] = f2b(W[p]);
    } else {
        int j = t - 123904;                    // 512 phases
        int sj = (j & ~31) + permrow(j & 31);
        phP[j] = INV2PI * ph[sj];
    }
}

// ---------------- fused prior + data: register-direct, zero main-loop LDS ----
// 4 waves, each owns a K-quarter (256 m / 128 l) for all 64 so x 64 n.
// Producer MFMA -> exp2/cos -> packed bf16 IS the consumer B-fragment (via
// the storage permutation). No tile, no barriers until the 3-barrier
// epilogue reduction of the 4 wave-partials.
__global__ __launch_bounds__(256, 4) void fused_kernel(
    const float* __restrict__ x,
    const short* __restrict__ zb, const short* __restrict__ FbB,
    const short* __restrict__ BWd, const short* __restrict__ Wtb,
    const float* __restrict__ nz2P, const float* __restrict__ phP,
    float* __restrict__ out)
{
    __shared__ float x2c[64];
    __shared__ __align__(16) float rbufA[64 * 68];
    __shared__ __align__(16) float rbufB[64 * 68];

    const int tid = threadIdx.x;
    const int lane = tid & 63, w = tid >> 6;
    const int q = lane >> 4, c = lane & 15;
    const int n0 = blockIdx.x * 64;

    if (tid < 64) {
        float s = 0.f;
        const float4v* xr = (const float4v*)(x + (size_t)(n0 + tid) * 16);
        #pragma unroll
        for (int k = 0; k < 4; k++) {
            float4v v = xr[k];
            float a0 = b2f(f2b(v.x)), a1 = b2f(f2b(v.y));
            float a2 = b2f(f2b(v.z)), a3 = b2f(f2b(v.w));
            s += a0 * a0 + a1 * a1 + a2 * a2 + a3 * a3;
        }
        x2c[tid] = 0.5f * LOG2E * s;
    }

    // x B-fragments for the 4 n-groups (K=16 real, quads 2,3 zero)
    short8 ax[4];
    #pragma unroll
    for (int nt = 0; nt < 4; nt++) {
        ax[nt] = (short8)0;
        if (q < 2) {
            const float4v* xp = (const float4v*)(x + (size_t)(n0 + nt * 16 + c) * 16 + q * 8);
            float4v v0 = xp[0], v1 = xp[1];
            ax[nt][0] = f2b(v0.x); ax[nt][1] = f2b(v0.y);
            ax[nt][2] = f2b(v0.z); ax[nt][3] = f2b(v0.w);
            ax[nt][4] = f2b(v1.x); ax[nt][5] = f2b(v1.y);
            ax[nt][6] = f2b(v1.z); ax[nt][7] = f2b(v1.w);
        }
    }

    float4v acc[4][4];
    #pragma unroll
    for (int a = 0; a < 4; a++)
        #pragma unroll
        for (int nt = 0; nt < 4; nt++) acc[a][nt] = (float4v)(0.f);

    __syncthreads();   // x2c ready

    // ============ data: exp2(x.z*log2e - z2) @ W^T, wave-private 256 m ============
    const int mbase = w * 256;
    #pragma unroll 2
    for (int mb = 0; mb < 8; mb++) {
        const int m0 = mbase + mb * 32;
        short8 bzA = (short8)0, bzB = (short8)0;
        if (q < 2) {
            bzA = *(const short8*)(zb + (size_t)(m0 + c) * 16 + q * 8);
            bzB = *(const short8*)(zb + (size_t)(m0 + 16 + c) * 16 + q * 8);
        }
        float4v c0A = *(const float4v*)(nz2P + m0 + 4 * q);
        float4v c0B = *(const float4v*)(nz2P + m0 + 16 + 4 * q);
        short8 pb[4];
        #pragma unroll
        for (int nt = 0; nt < 4; nt++) {
            float4v dA = __builtin_amdgcn_mfma_f32_16x16x32_bf16(bzA, ax[nt], c0A, 0, 0, 0);
            float4v dB = __builtin_amdgcn_mfma_f32_16x16x32_bf16(bzB, ax[nt], c0B, 0, 0, 0);
            uint4v u;
            u[0] = pk2(EXP2F(dA[0]), EXP2F(dA[1]));
            u[1] = pk2(EXP2F(dA[2]), EXP2F(dA[3]));
            u[2] = pk2(EXP2F(dB[0]), EXP2F(dB[1]));
            u[3] = pk2(EXP2F(dB[2]), EXP2F(dB[3]));
            pb[nt] = __builtin_bit_cast(short8, u);
        }
        #pragma unroll
        for (int a = 0; a < 4; a++) {
            short8 aw = *(const short8*)(Wtb + (size_t)(a * 16 + c) * 1024 + m0 + q * 8);
            #pragma unroll
            for (int nt = 0; nt < 4; nt++)
                acc[a][nt] = __builtin_amdgcn_mfma_f32_16x16x32_bf16(aw, pb[nt], acc[a][nt], 0, 0, 0);
        }
    }

    // scale data part by exp2(-x2[n])
    #pragma unroll
    for (int nt = 0; nt < 4; nt++) {
        float sxv = EXP2F(-x2c[nt * 16 + c]);
        #pragma unroll
        for (int a = 0; a < 4; a++) acc[a][nt] *= sxv;
    }

    // ============ prior: cos(2pi*(x.F/2pi + ph/2pi)) @ blockdiag(pws) ============
    const int lbase = w * 128;
    #pragma unroll 2
    for (int lb = 0; lb < 4; lb++) {
        const int l0 = lbase + lb * 32;
        short8 bfA = (short8)0, bfB = (short8)0;
        if (q < 2) {
            bfA = *(const short8*)(FbB + (size_t)(l0 + c) * 16 + q * 8);
            bfB = *(const short8*)(FbB + (size_t)(l0 + 16 + c) * 16 + q * 8);
        }
        float4v c0A = *(const float4v*)(phP + l0 + 4 * q);
        float4v c0B = *(const float4v*)(phP + l0 + 16 + 4 * q);
        short8 pb[4];
        #pragma unroll
        for (int nt = 0; nt < 4; nt++) {
            float4v dA = __builtin_amdgcn_mfma_f32_16x16x32_bf16(bfA, ax[nt], c0A, 0, 0, 0);
            float4v dB = __builtin_amdgcn_mfma_f32_16x16x32_bf16(bfB, ax[nt], c0B, 0, 0, 0);
            uint4v u;
            u[0] = pk2(COSR(dA[0]), COSR(dA[1]));
            u[1] = pk2(COSR(dA[2]), COSR(dA[3]));
            u[2] = pk2(COSR(dB[0]), COSR(dB[1]));
            u[3] = pk2(COSR(dB[2]), COSR(dB[3]));
            pb[nt] = __builtin_bit_cast(short8, u);
        }
        #pragma unroll
        for (int a = 0; a < 4; a++) {
            short8 aw = *(const short8*)(BWd + (size_t)(a * 16 + c) * 512 + l0 + q * 8);
            #pragma unroll
            for (int nt = 0; nt < 4; nt++)
                acc[a][nt] = __builtin_amdgcn_mfma_f32_16x16x32_bf16(aw, pb[nt], acc[a][nt], 0, 0, 0);
        }
    }

    // ============ epilogue: reduce 4 wave-partials, store ============
    __syncthreads();
    if (w & 1) {                       // w1 -> A, w3 -> B
        float* rb = (w == 1) ? rbufA : rbufB;
        #pragma unroll
        for (int a = 0; a < 4; a++)
            #pragma unroll
            for (int nt = 0; nt < 4; nt++)
                #pragma unroll
                for (int r = 0; r < 4; r++)
                    rb[(a * 16 + 4 * q + r) * 68 + nt * 16 + c] = acc[a][nt][r];
    }
    __syncthreads();
    if (!(w & 1)) {                    // w0 += into A, w2 += into B
        float* rb = (w == 0) ? rbufA : rbufB;
        #pragma unroll
        for (int a = 0; a < 4; a++)
            #pragma unroll
            for (int nt = 0; nt < 4; nt++)
                #pragma unroll
                for (int r = 0; r < 4; r++) {
                    int idx = (a * 16 + 4 * q + r) * 68 + nt * 16 + c;
                    rb[idx] += acc[a][nt][r];
                }
    }
    __syncthreads();
    #pragma unroll
    for (int k = 0; k < 16; k++) {     // out = A + B, row-coalesced
        int idx = k * 256 + tid;
        int row = idx >> 6, nn = idx & 63;
        out[(size_t)row * N_PTS + n0 + nn] = rbufA[row * 68 + nn] + rbufB[row * 68 + nn];
    }
}

extern "C" void kernel_launch(void* const* d_in, const int* in_sizes, int n_in,
                              void* d_out, int out_size, void* d_ws, size_t ws_size,
                              hipStream_t stream) {
    const float* x  = (const float*)d_in[0];   // [65536][16]
    const float* z  = (const float*)d_in[1];   // [1024][16]
    const float* W  = (const float*)d_in[2];   // [8][8][1024] = [64][1024]
    const float* F  = (const float*)d_in[3];   // [8][16][64]
    const float* ph = (const float*)d_in[4];   // [8][64]
    const float* pw = (const float*)d_in[5];   // [8][8][64] = [64][64]
    float* out = (float*)d_out;                // [64][65536]

    char* ws = (char*)d_ws;
    short* zb   = (short*)(ws);            // 32768 B
    short* FbB  = (short*)(ws + 32768);    // 16384 B
    short* BWd  = (short*)(ws + 49152);    // 65536 B
    short* Wtb  = (short*)(ws + 114688);   // 131072 B
    float* nz2P = (float*)(ws + 245760);   // 4096 B
    float* phP  = (float*)(ws + 249856);   // 2048 B

    prep_kernel<<<486, 256, 0, stream>>>(z, W, F, pw, ph, zb, FbB, BWd, Wtb, nz2P, phP);
    fused_kernel<<<1024, 256, 0, stream>>>(x, zb, FbB, BWd, Wtb, nz2P, phP, out);
}

// Round 6
// 106.574 us; speedup vs baseline: 1.1896x; 1.0818x over previous
//
#include <hip/hip_runtime.h>
#include <hip/hip_bf16.h>

#define N_PTS 65536
#define LOG2E 1.4426950408889634f
#define INV2PI 0.15915494309189535f

typedef __attribute__((ext_vector_type(8))) short short8;
typedef __attribute__((ext_vector_type(4))) short short4v;
typedef __attribute__((ext_vector_type(4))) float float4v;

#if __has_builtin(__builtin_amdgcn_exp2f)
#define EXP2F(x) __builtin_amdgcn_exp2f(x)
#else
#define EXP2F(x) exp2f(x)
#endif

// cos on REVOLUTIONS (inputs pre-scaled by 1/2pi in prep): v_fract + v_cos.
#if __has_builtin(__builtin_amdgcn_cosf) && __has_builtin(__builtin_amdgcn_fractf)
#define COSR(x) __builtin_amdgcn_cosf(__builtin_amdgcn_fractf(x))
#else
#define COSR(x) __cosf((x) * 6.283185307179586f)
#endif

__device__ __forceinline__ short f2b(float f) {
    __hip_bfloat16 h = __float2bfloat16(f);
    return *(short*)&h;
}
__device__ __forceinline__ float b2f(short s) {
    __hip_bfloat16 h = *(__hip_bfloat16*)&s;
    return __bfloat162float(h);
}

// ---- producer MFMA: K=16 native if available (halves producer regs+cycles),
// ---- else R2's masked 16x16x32 (identical math). D-layout identical.
#if __has_builtin(__builtin_amdgcn_mfma_f32_16x16x16bf16_1k)
#define HAVE_MFMA16 1
typedef short4v pafrag;
__device__ __forceinline__ float4v pmfma(pafrag a, pafrag b, float4v c) {
    return __builtin_amdgcn_mfma_f32_16x16x16bf16_1k(a, b, c, 0, 0, 0);
}
#else
#define HAVE_MFMA16 0
typedef short8 pafrag;
__device__ __forceinline__ float4v pmfma(pafrag a, pafrag b, float4v c) {
    return __builtin_amdgcn_mfma_f32_16x16x32_bf16(a, b, c, 0, 0, 0);
}
#endif

// A-fragment from a [rows][16] bf16 table: lane (q,c) -> row base+c, k-dims.
__device__ __forceinline__ pafrag ldrow(const short* base, int row16, int q, int c) {
#if HAVE_MFMA16
    return *(const pafrag*)(base + (size_t)(row16 + c) * 16 + 4 * q);
#else
    pafrag v = (pafrag)0;
    if (q < 2) v = *(const pafrag*)(base + (size_t)(row16 + c) * 16 + 8 * q);
    return v;
#endif
}
// B-fragment from x (f32 [n][16]): lane (q,c) -> col row, k-dims.
__device__ __forceinline__ pafrag mkxfrag(const float* x, size_t row, int q) {
#if HAVE_MFMA16
    float4v v = *(const float4v*)(x + row * 16 + 4 * q);
    pafrag a;
    a[0] = f2b(v.x); a[1] = f2b(v.y); a[2] = f2b(v.z); a[3] = f2b(v.w);
    return a;
#else
    pafrag a = (pafrag)0;
    if (q < 2) {
        const float4v* xp = (const float4v*)(x + row * 16 + 8 * q);
        float4v v0 = xp[0], v1 = xp[1];
        a[0] = f2b(v0.x); a[1] = f2b(v0.y); a[2] = f2b(v0.z); a[3] = f2b(v0.w);
        a[4] = f2b(v1.x); a[5] = f2b(v1.y); a[6] = f2b(v1.z); a[7] = f2b(v1.w);
    }
    return a;
#endif
}

// K-permutation: within each 32-row group, storage row p holds source row
// perm(p). Chunk A (p<16) -> m {0-3,8-11,16-19,24-27}; chunk B -> +4.
// Producer D-reg r at lane q (chunk A row 4q+r) => m = 8q+r; chunk B => 8q+4+r.
// So [dA[0..3], dB[0..3]] at lane q == consumer B-fragment k = 8q..8q+7. No LDS.
__device__ __forceinline__ int permrow(int p) {
    return ((p & 12) << 1) + (p & 3) + ((p >> 4) << 2);
}

// ---------------- prep ----------------
// ws layout (bytes):
//   zb   [1024][16] bf16  @ 0        row-PERMUTED bf16(log2e * z)
//   FbB  [512][16] bf16   @ 32768    row-PERMUTED bf16(F^T / 2pi)  (rows = o*64+l)
//   BWd  [64][512] bf16   @ 49152    block-diag sqrt(2/64)*pw (natural cols)
//   Wtb  [64][1024] bf16  @ 114688   bf16(W) (natural cols)
//   nz2P [1024] f32       @ 245760   PERMUTED  -0.5*log2e*||bf16(z_m)||^2
//   phP  [512] f32        @ 249856   PERMUTED  phases / 2pi
__global__ __launch_bounds__(256) void prep_kernel(
    const float* __restrict__ z, const float* __restrict__ W,
    const float* __restrict__ F, const float* __restrict__ pw,
    const float* __restrict__ ph,
    short* __restrict__ zb, short* __restrict__ FbB,
    short* __restrict__ BWd, short* __restrict__ Wtb,
    float* __restrict__ nz2P, float* __restrict__ phP)
{
    int t = blockIdx.x * 256 + threadIdx.x;
    if (t < 16384) {
        int row = t >> 4, i = t & 15;
        int src = (row & ~31) + permrow(row & 31);
        zb[t] = f2b(LOG2E * z[src * 16 + i]);
    } else if (t < 17408) {
        int m = t - 16384;
        int src = (m & ~31) + permrow(m & 31);
        const float4v* zp = (const float4v*)(z + (size_t)src * 16);
        float s = 0.f;
        #pragma unroll
        for (int k = 0; k < 4; k++) {
            float4v v = zp[k];
            float a0 = b2f(f2b(v.x)), a1 = b2f(f2b(v.y));
            float a2 = b2f(f2b(v.z)), a3 = b2f(f2b(v.w));
            s += a0 * a0 + a1 * a1 + a2 * a2 + a3 * a3;
        }
        nz2P[m] = -(0.5f * LOG2E * s);
    } else if (t < 25600) {
        int p = t - 17408;
        int row = p >> 4, i = p & 15;
        int srow = (row & ~31) + permrow(row & 31);
        int o = srow >> 6, l = srow & 63;
        FbB[p] = f2b(INV2PI * F[o * 1024 + i * 64 + l]);
    } else if (t < 58368) {
        int p = t - 25600;
        int so = p >> 9, ol = p & 511, o = ol >> 6;
        float v = ((so & 7) == o) ? 0.17677669529663687f * pw[so * 64 + (ol & 63)] : 0.f;
        BWd[p] = f2b(v);
    } else if (t < 123904) {
        int p = t - 58368;
        Wtb[p] = f2b(W[p]);
    } else {
        int j = t - 123904;                    // 512 phases
        int sj = (j & ~31) + permrow(j & 31);
        phP[j] = INV2PI * ph[sj];
    }
}

// ---------------- fused prior + data: register-direct, zero main-loop LDS ----
// 4 waves, each owns a K-quarter (256 m / 128 l) for all 64 so x 64 n.
// Chunk schedule (nt-outer): load bz/c0 then aw[4] at top; per nt the
// producer MFMA->trans->pack feeds 4 consumer MFMAs immediately (pb live = 4
// regs), so aw[4] stays resident and its L2 latency hides under nt=0's
// producer. trans of nt overlaps consumer MFMAs of nt-1 (separate pipes).
__global__ __launch_bounds__(256, 4) void fused_kernel(
    const float* __restrict__ x,
    const short* __restrict__ zb, const short* __restrict__ FbB,
    const short* __restrict__ BWd, const short* __restrict__ Wtb,
    const float* __restrict__ nz2P, const float* __restrict__ phP,
    float* __restrict__ out)
{
    __shared__ float x2c[64];
    __shared__ __align__(16) float rbufA[64 * 68];
    __shared__ __align__(16) float rbufB[64 * 68];

    const int tid = threadIdx.x;
    const int lane = tid & 63, w = tid >> 6;
    const int q = lane >> 4, c = lane & 15;
    const int n0 = blockIdx.x * 64;

    if (tid < 64) {
        float s = 0.f;
        const float4v* xr = (const float4v*)(x + (size_t)(n0 + tid) * 16);
        #pragma unroll
        for (int k = 0; k < 4; k++) {
            float4v v = xr[k];
            float a0 = b2f(f2b(v.x)), a1 = b2f(f2b(v.y));
            float a2 = b2f(f2b(v.z)), a3 = b2f(f2b(v.w));
            s += a0 * a0 + a1 * a1 + a2 * a2 + a3 * a3;
        }
        x2c[tid] = 0.5f * LOG2E * s;
    }

    // x B-fragments for the 4 n-groups
    pafrag ax[4];
    #pragma unroll
    for (int nt = 0; nt < 4; nt++)
        ax[nt] = mkxfrag(x, (size_t)(n0 + nt * 16 + c), q);

    float4v acc[4][4];
    #pragma unroll
    for (int a = 0; a < 4; a++)
        #pragma unroll
        for (int nt = 0; nt < 4; nt++) acc[a][nt] = (float4v)(0.f);

    __syncthreads();   // x2c ready

    // ============ data: exp2(x.z*log2e - z2) @ W^T, wave-private 256 m ============
    const int mbase = w * 256;
    #pragma unroll 2
    for (int mb = 0; mb < 8; mb++) {
        const int m0 = mbase + mb * 32;
        // producer deps first, consumer weights last (latency shadow = producer)
        pafrag bzA = ldrow(zb, m0, q, c);
        pafrag bzB = ldrow(zb, m0 + 16, q, c);
        float4v c0A = *(const float4v*)(nz2P + m0 + 4 * q);
        float4v c0B = *(const float4v*)(nz2P + m0 + 16 + 4 * q);
        short8 aw0 = *(const short8*)(Wtb + (size_t)(0 * 16 + c) * 1024 + m0 + q * 8);
        short8 aw1 = *(const short8*)(Wtb + (size_t)(1 * 16 + c) * 1024 + m0 + q * 8);
        short8 aw2 = *(const short8*)(Wtb + (size_t)(2 * 16 + c) * 1024 + m0 + q * 8);
        short8 aw3 = *(const short8*)(Wtb + (size_t)(3 * 16 + c) * 1024 + m0 + q * 8);
        #pragma unroll
        for (int nt = 0; nt < 4; nt++) {
            float4v dA = pmfma(bzA, ax[nt], c0A);
            float4v dB = pmfma(bzB, ax[nt], c0B);
            short8 pb;
            pb[0] = f2b(EXP2F(dA[0])); pb[1] = f2b(EXP2F(dA[1]));
            pb[2] = f2b(EXP2F(dA[2])); pb[3] = f2b(EXP2F(dA[3]));
            pb[4] = f2b(EXP2F(dB[0])); pb[5] = f2b(EXP2F(dB[1]));
            pb[6] = f2b(EXP2F(dB[2])); pb[7] = f2b(EXP2F(dB[3]));
            acc[0][nt] = __builtin_amdgcn_mfma_f32_16x16x32_bf16(aw0, pb, acc[0][nt], 0, 0, 0);
            acc[1][nt] = __builtin_amdgcn_mfma_f32_16x16x32_bf16(aw1, pb, acc[1][nt], 0, 0, 0);
            acc[2][nt] = __builtin_amdgcn_mfma_f32_16x16x32_bf16(aw2, pb, acc[2][nt], 0, 0, 0);
            acc[3][nt] = __builtin_amdgcn_mfma_f32_16x16x32_bf16(aw3, pb, acc[3][nt], 0, 0, 0);
        }
    }

    // scale data part by exp2(-x2[n])
    #pragma unroll
    for (int nt = 0; nt < 4; nt++) {
        float sxv = EXP2F(-x2c[nt * 16 + c]);
        #pragma unroll
        for (int a = 0; a < 4; a++) acc[a][nt] *= sxv;
    }

    // ============ prior: cos(2pi*(x.F/2pi + ph/2pi)) @ blockdiag(pws) ============
    const int lbase = w * 128;
    #pragma unroll 2
    for (int lb = 0; lb < 4; lb++) {
        const int l0 = lbase + lb * 32;
        pafrag bfA = ldrow(FbB, l0, q, c);
        pafrag bfB = ldrow(FbB, l0 + 16, q, c);
        float4v c0A = *(const float4v*)(phP + l0 + 4 * q);
        float4v c0B = *(const float4v*)(phP + l0 + 16 + 4 * q);
        short8 aw0 = *(const short8*)(BWd + (size_t)(0 * 16 + c) * 512 + l0 + q * 8);
        short8 aw1 = *(const short8*)(BWd + (size_t)(1 * 16 + c) * 512 + l0 + q * 8);
        short8 aw2 = *(const short8*)(BWd + (size_t)(2 * 16 + c) * 512 + l0 + q * 8);
        short8 aw3 = *(const short8*)(BWd + (size_t)(3 * 16 + c) * 512 + l0 + q * 8);
        #pragma unroll
        for (int nt = 0; nt < 4; nt++) {
            float4v dA = pmfma(bfA, ax[nt], c0A);
            float4v dB = pmfma(bfB, ax[nt], c0B);
            short8 pb;
            pb[0] = f2b(COSR(dA[0])); pb[1] = f2b(COSR(dA[1]));
            pb[2] = f2b(COSR(dA[2])); pb[3] = f2b(COSR(dA[3]));
            pb[4] = f2b(COSR(dB[0])); pb[5] = f2b(COSR(dB[1]));
            pb[6] = f2b(COSR(dB[2])); pb[7] = f2b(COSR(dB[3]));
            acc[0][nt] = __builtin_amdgcn_mfma_f32_16x16x32_bf16(aw0, pb, acc[0][nt], 0, 0, 0);
            acc[1][nt] = __builtin_amdgcn_mfma_f32_16x16x32_bf16(aw1, pb, acc[1][nt], 0, 0, 0);
            acc[2][nt] = __builtin_amdgcn_mfma_f32_16x16x32_bf16(aw2, pb, acc[2][nt], 0, 0, 0);
            acc[3][nt] = __builtin_amdgcn_mfma_f32_16x16x32_bf16(aw3, pb, acc[3][nt], 0, 0, 0);
        }
    }

    // ============ epilogue: reduce 4 wave-partials, store ============
    __syncthreads();
    if (w & 1) {                       // w1 -> A, w3 -> B
        float* rb = (w == 1) ? rbufA : rbufB;
        #pragma unroll
        for (int a = 0; a < 4; a++)
            #pragma unroll
            for (int nt = 0; nt < 4; nt++)
                #pragma unroll
                for (int r = 0; r < 4; r++)
                    rb[(a * 16 + 4 * q + r) * 68 + nt * 16 + c] = acc[a][nt][r];
    }
    __syncthreads();
    if (!(w & 1)) {                    // w0 += into A, w2 += into B
        float* rb = (w == 0) ? rbufA : rbufB;
        #pragma unroll
        for (int a = 0; a < 4; a++)
            #pragma unroll
            for (int nt = 0; nt < 4; nt++)
                #pragma unroll
                for (int r = 0; r < 4; r++) {
                    int idx = (a * 16 + 4 * q + r) * 68 + nt * 16 + c;
                    rb[idx] += acc[a][nt][r];
                }
    }
    __syncthreads();
    #pragma unroll
    for (int k = 0; k < 16; k++) {     // out = A + B, row-coalesced
        int idx = k * 256 + tid;
        int row = idx >> 6, nn = idx & 63;
        out[(size_t)row * N_PTS + n0 + nn] = rbufA[row * 68 + nn] + rbufB[row * 68 + nn];
    }
}

extern "C" void kernel_launch(void* const* d_in, const int* in_sizes, int n_in,
                              void* d_out, int out_size, void* d_ws, size_t ws_size,
                              hipStream_t stream) {
    const float* x  = (const float*)d_in[0];   // [65536][16]
    const float* z  = (const float*)d_in[1];   // [1024][16]
    const float* W  = (const float*)d_in[2];   // [8][8][1024] = [64][1024]
    const float* F  = (const float*)d_in[3];   // [8][16][64]
    const float* ph = (const float*)d_in[4];   // [8][64]
    const float* pw = (const float*)d_in[5];   // [8][8][64] = [64][64]
    float* out = (float*)d_out;                // [64][65536]

    char* ws = (char*)d_ws;
    short* zb   = (short*)(ws);            // 32768 B
    short* FbB  = (short*)(ws + 32768);    // 16384 B
    short* BWd  = (short*)(ws + 49152);    // 65536 B
    short* Wtb  = (short*)(ws + 114688);   // 131072 B
    float* nz2P = (float*)(ws + 245760);   // 4096 B
    float* phP  = (float*)(ws + 249856);   // 2048 B

    prep_kernel<<<486, 256, 0, stream>>>(z, W, F, pw, ph, zb, FbB, BWd, Wtb, nz2P, phP);
    fused_kernel<<<1024, 256, 0, stream>>>(x, zb, FbB, BWd, Wtb, nz2P, phP, out);
}